// Round 2
// baseline (162.760 us; speedup 1.0000x reference)
//
#include <hip/hip_runtime.h>

#define NTOK 4096
#define DMODEL 512
#define DEMB 64
#define DCAT 576
#define NHEAD 8
#define DHEAD 64

typedef float f32x4 __attribute__((ext_vector_type(4)));
typedef short s16x8 __attribute__((ext_vector_type(8)));
typedef unsigned short u16;
typedef u16 u16x4 __attribute__((ext_vector_type(4)));
typedef u16 u16x8 __attribute__((ext_vector_type(8)));
typedef unsigned int u32;

__device__ __forceinline__ u16 f2bf(float f) {
  union { float f; unsigned u; } v; v.f = f;
  unsigned r = v.u + 0x7fffu + ((v.u >> 16) & 1u);
  return (u16)(r >> 16);
}

__device__ __forceinline__ void gload16(const void* g, void* lds) {
  __builtin_amdgcn_global_load_lds((const __attribute__((address_space(1))) u32*)g,
                                   (__attribute__((address_space(3))) u32*)lds, 16, 0, 0);
}

// ---------------- weight transpose fp32 -> bf16 [out][in] ----------------
__global__ void wtrans_kernel(const float* __restrict__ Wq, const float* __restrict__ Wk,
                              const float* __restrict__ Wv, const float* __restrict__ Wf1,
                              const float* __restrict__ Wf2,
                              u16* __restrict__ Tq, u16* __restrict__ Tk, u16* __restrict__ Tv,
                              u16* __restrict__ Tf1, u16* __restrict__ Tf2) {
  __shared__ float tile[64][65];
  int w = blockIdx.z;
  const float* src; u16* dst; int K;
  if (w == 0)      { src = Wq;  dst = Tq;  K = DCAT; }
  else if (w == 1) { src = Wk;  dst = Tk;  K = DCAT; }
  else if (w == 2) { src = Wv;  dst = Tv;  K = DMODEL; }
  else if (w == 3) { src = Wf1; dst = Tf1; K = DMODEL; }
  else             { src = Wf2; dst = Tf2; K = DMODEL; }
  int kb = blockIdx.x * 64;
  if (kb >= K) return;
  int nb = blockIdx.y * 64;
  int tid = threadIdx.x;
  #pragma unroll
  for (int i = 0; i < 16; ++i) {
    int idx = tid + i * 256;
    int r = idx >> 6, c = idx & 63;
    tile[r][c] = src[(size_t)(kb + r) * DMODEL + nb + c];
  }
  __syncthreads();
  #pragma unroll
  for (int i = 0; i < 16; ++i) {
    int idx = tid + i * 256;
    int r = idx >> 6, c = idx & 63;
    dst[(size_t)(nb + r) * K + kb + c] = f2bf(tile[c][r]);
  }
}

// ---------------- LayerNorm x: write xt (f32) + qk_in[:, :512] (bf16) ----------------
__global__ void lnx_kernel(const float* __restrict__ x, const float* __restrict__ g,
                           const float* __restrict__ b, float* __restrict__ xt,
                           u16* __restrict__ qkin) {
  int row = blockIdx.x * 4 + (threadIdx.x >> 6);
  int lane = threadIdx.x & 63;
  const float* xr = x + (size_t)row * DMODEL + lane * 8;
  float v[8];
  float4 a0 = *(const float4*)xr;
  float4 a1 = *(const float4*)(xr + 4);
  v[0]=a0.x; v[1]=a0.y; v[2]=a0.z; v[3]=a0.w; v[4]=a1.x; v[5]=a1.y; v[6]=a1.z; v[7]=a1.w;
  float s = 0.f, ss = 0.f;
  #pragma unroll
  for (int j = 0; j < 8; ++j) { s += v[j]; ss += v[j]*v[j]; }
  #pragma unroll
  for (int off = 32; off > 0; off >>= 1) { s += __shfl_xor(s, off); ss += __shfl_xor(ss, off); }
  float mu = s * (1.0f / DMODEL);
  float var = ss * (1.0f / DMODEL) - mu * mu;
  float rs = rsqrtf(var + 1e-5f);
  float4 g0 = *(const float4*)(g + lane * 8);
  float4 g1v = *(const float4*)(g + lane * 8 + 4);
  float4 b0 = *(const float4*)(b + lane * 8);
  float4 b1v = *(const float4*)(b + lane * 8 + 4);
  float gg[8] = {g0.x,g0.y,g0.z,g0.w,g1v.x,g1v.y,g1v.z,g1v.w};
  float bb[8] = {b0.x,b0.y,b0.z,b0.w,b1v.x,b1v.y,b1v.z,b1v.w};
  float o[8]; u16x8 ob;
  #pragma unroll
  for (int j = 0; j < 8; ++j) { o[j] = (v[j]-mu)*rs*gg[j] + bb[j]; ob[j] = f2bf(o[j]); }
  float* xo = xt + (size_t)row * DMODEL + lane * 8;
  *(float4*)xo = make_float4(o[0],o[1],o[2],o[3]);
  *(float4*)(xo + 4) = make_float4(o[4],o[5],o[6],o[7]);
  *(u16x8*)(qkin + (size_t)row * DCAT + lane * 8) = ob;
}

// ---------------- LayerNorm emb: write qk_in[:, 512:576] (bf16) ----------------
__global__ void lne_kernel(const float* __restrict__ e, const float* __restrict__ g,
                           const float* __restrict__ b, u16* __restrict__ qkin) {
  int row = blockIdx.x * 4 + (threadIdx.x >> 6);
  int lane = threadIdx.x & 63;
  float v = e[(size_t)row * DEMB + lane];
  float s = v, ss = v * v;
  #pragma unroll
  for (int off = 32; off > 0; off >>= 1) { s += __shfl_xor(s, off); ss += __shfl_xor(ss, off); }
  float mu = s * (1.0f / DEMB);
  float var = ss * (1.0f / DEMB) - mu * mu;
  float rs = rsqrtf(var + 1e-5f);
  float o = (v - mu) * rs * g[lane] + b[lane];
  qkin[(size_t)row * DCAT + DMODEL + lane] = f2bf(o);
}

// ---------------- LayerNorm 3: xt (f32) -> h (bf16) ----------------
__global__ void ln3_kernel(const float* __restrict__ xt, const float* __restrict__ g,
                           const float* __restrict__ b, u16* __restrict__ hb) {
  int row = blockIdx.x * 4 + (threadIdx.x >> 6);
  int lane = threadIdx.x & 63;
  const float* xr = xt + (size_t)row * DMODEL + lane * 8;
  float v[8];
  float4 a0 = *(const float4*)xr;
  float4 a1 = *(const float4*)(xr + 4);
  v[0]=a0.x; v[1]=a0.y; v[2]=a0.z; v[3]=a0.w; v[4]=a1.x; v[5]=a1.y; v[6]=a1.z; v[7]=a1.w;
  float s = 0.f, ss = 0.f;
  #pragma unroll
  for (int j = 0; j < 8; ++j) { s += v[j]; ss += v[j]*v[j]; }
  #pragma unroll
  for (int off = 32; off > 0; off >>= 1) { s += __shfl_xor(s, off); ss += __shfl_xor(ss, off); }
  float mu = s * (1.0f / DMODEL);
  float var = ss * (1.0f / DMODEL) - mu * mu;
  float rs = rsqrtf(var + 1e-5f);
  float4 g0 = *(const float4*)(g + lane * 8);
  float4 g1v = *(const float4*)(g + lane * 8 + 4);
  float4 b0 = *(const float4*)(b + lane * 8);
  float4 b1v = *(const float4*)(b + lane * 8 + 4);
  float gg[8] = {g0.x,g0.y,g0.z,g0.w,g1v.x,g1v.y,g1v.z,g1v.w};
  float bb[8] = {b0.x,b0.y,b0.z,b0.w,b1v.x,b1v.y,b1v.z,b1v.w};
  u16x8 ob;
  #pragma unroll
  for (int j = 0; j < 8; ++j) ob[j] = f2bf((v[j]-mu)*rs*gg[j] + bb[j]);
  *(u16x8*)(hb + (size_t)row * DMODEL + lane * 8) = ob;
}

// ---------------- GEMM: C[M=4096, 512] = A[M,K] @ Bt^T, Bt is [512][K] bf16 ----------------
// MODE 0: Q  -> scale 1/8, head layout [H][N][64] bf16
// MODE 1: K  -> head layout bf16
// MODE 2: V  -> transposed layout vT[512][4096] bf16
// MODE 3: FFN1 -> bias + relu, row-major bf16
// MODE 4: FFN2 -> bias + xt residual, f32 out
template<int MODE>
__global__ __launch_bounds__(256) void gemm_kernel(
    const u16* __restrict__ A, int lda, const u16* __restrict__ Bt, int K,
    u16* __restrict__ outb, float* __restrict__ outf,
    const float* __restrict__ bias, const float* __restrict__ xt) {
  __shared__ __align__(16) u16 smem[12288];  // A: [128][64] at 0, B: [64][64] at 8192
  u16* Al = smem;
  u16* Bl = smem + 8192;
  int tid = threadIdx.x, lane = tid & 63, wid = tid >> 6;
  int li = lane & 15, g4 = lane >> 4;
  int mt = blockIdx.x >> 3, nt = blockIdx.x & 7;
  int m0 = mt * 128, n0 = nt * 64;
  int wr = (wid >> 1) * 64, wc = (wid & 1) * 32;
  f32x4 acc[4][2] = {};
  for (int k0 = 0; k0 < K; k0 += 64) {
    #pragma unroll
    for (int i = 0; i < 4; ++i) {
      int c = i * 256 + wid * 64 + lane;
      int row = c >> 3, cb = (c & 7) * 8;
      gload16(A + (size_t)(m0 + row) * lda + k0 + cb, (char*)Al + (i * 256 + wid * 64) * 16);
    }
    #pragma unroll
    for (int i = 0; i < 2; ++i) {
      int c = i * 256 + wid * 64 + lane;
      int row = c >> 3, cb = (c & 7) * 8;
      gload16(Bt + (size_t)(n0 + row) * K + k0 + cb, (char*)Bl + (i * 256 + wid * 64) * 16);
    }
    __syncthreads();
    #pragma unroll
    for (int kk = 0; kk < 2; ++kk) {
      s16x8 af[4], bfv[2];
      #pragma unroll
      for (int mi = 0; mi < 4; ++mi)
        af[mi] = *(const s16x8*)&Al[(wr + mi * 16 + li) * 64 + kk * 32 + g4 * 8];
      #pragma unroll
      for (int ni = 0; ni < 2; ++ni)
        bfv[ni] = *(const s16x8*)&Bl[(wc + ni * 16 + li) * 64 + kk * 32 + g4 * 8];
      #pragma unroll
      for (int mi = 0; mi < 4; ++mi)
        #pragma unroll
        for (int ni = 0; ni < 2; ++ni)
          acc[mi][ni] = __builtin_amdgcn_mfma_f32_16x16x32_bf16(af[mi], bfv[ni], acc[mi][ni], 0, 0, 0);
    }
    __syncthreads();
  }
  if (MODE <= 1) {
    float scale = (MODE == 0) ? 0.125f : 1.0f;
    #pragma unroll
    for (int mi = 0; mi < 4; ++mi)
      #pragma unroll
      for (int ni = 0; ni < 2; ++ni) {
        int col = n0 + wc + ni * 16 + li;
        int h = col >> 6, dh = col & 63;
        #pragma unroll
        for (int r = 0; r < 4; ++r) {
          int row = m0 + wr + mi * 16 + g4 * 4 + r;
          outb[((size_t)h * NTOK + row) * DHEAD + dh] = f2bf(acc[mi][ni][r] * scale);
        }
      }
  } else if (MODE == 2) {
    u16* tp = smem;  // [64][136]
    #pragma unroll
    for (int mi = 0; mi < 4; ++mi)
      #pragma unroll
      for (int ni = 0; ni < 2; ++ni) {
        int cl = wc + ni * 16 + li;
        int r0 = wr + mi * 16 + g4 * 4;
        u16x4 pk;
        pk[0] = f2bf(acc[mi][ni][0]); pk[1] = f2bf(acc[mi][ni][1]);
        pk[2] = f2bf(acc[mi][ni][2]); pk[3] = f2bf(acc[mi][ni][3]);
        *(u16x4*)&tp[cl * 136 + r0] = pk;
      }
    __syncthreads();
    for (int c = tid; c < 1024; c += 256) {
      int cl = c >> 4, seg = c & 15;
      u16x8 v = *(const u16x8*)&tp[cl * 136 + seg * 8];
      *(u16x8*)&outb[(size_t)(n0 + cl) * NTOK + m0 + seg * 8] = v;
    }
  } else {
    #pragma unroll
    for (int mi = 0; mi < 4; ++mi)
      #pragma unroll
      for (int ni = 0; ni < 2; ++ni) {
        int col = n0 + wc + ni * 16 + li;
        float bv = bias[col];
        #pragma unroll
        for (int r = 0; r < 4; ++r) {
          int row = m0 + wr + mi * 16 + g4 * 4 + r;
          float v = acc[mi][ni][r] + bv;
          if (MODE == 3) {
            v = fmaxf(v, 0.0f);
            outb[(size_t)row * DMODEL + col] = f2bf(v);
          } else {
            outf[(size_t)row * DMODEL + col] = v + xt[(size_t)row * DMODEL + col];
          }
        }
      }
  }
}

// ---------------- fused flash attention, adds into xt ----------------
// grid 512: head = bid & 7 (XCD locality), qtile = bid >> 3. 4 waves split keys 4-way.
__global__ __launch_bounds__(256, 2) void attn_kernel(
    const u16* __restrict__ qh, const u16* __restrict__ kh,
    const u16* __restrict__ vT, float* __restrict__ xt) {
  __shared__ __align__(16) u16 p_lds[4][4096];
  __shared__ float o_lds[64][64];
  __shared__ float ml_lds[4][2][64];
  int tid = threadIdx.x, lane = tid & 63, wid = tid >> 6;
  int li = lane & 15, g4 = lane >> 4;
  int h = blockIdx.x & 7, qt = blockIdx.x >> 3;
  int q0 = qt * 64;
  const u16* qbase = qh + ((size_t)h * NTOK + q0) * DHEAD;
  s16x8 bq[4][2];
  #pragma unroll
  for (int mi = 0; mi < 4; ++mi)
    #pragma unroll
    for (int kk = 0; kk < 2; ++kk)
      bq[mi][kk] = *(const s16x8*)(qbase + (mi * 16 + li) * DHEAD + kk * 32 + g4 * 8);
  f32x4 o[4][4] = {};
  float m_run[4], l_run[4];
  #pragma unroll
  for (int mi = 0; mi < 4; ++mi) { m_run[mi] = -1e30f; l_run[mi] = 0.f; }
  u16* myp = p_lds[wid];
  const u16* kh_h = kh + (size_t)h * NTOK * DHEAD;
  for (int t = 0; t < 16; ++t) {
    int kb = wid * 1024 + t * 64;
    const u16* kbase = kh_h + (size_t)kb * DHEAD;
    s16x8 ak[4][2];
    #pragma unroll
    for (int ni = 0; ni < 4; ++ni)
      #pragma unroll
      for (int kk = 0; kk < 2; ++kk)
        ak[ni][kk] = *(const s16x8*)(kbase + (ni * 16 + li) * DHEAD + kk * 32 + g4 * 8);
    // S^T = K * Q^T : D[key_local][q_local]; per lane q = mi*16+li, keys = ni*16 + g4*4 + r
    f32x4 st[4][4];
    #pragma unroll
    for (int ni = 0; ni < 4; ++ni)
      #pragma unroll
      for (int mi = 0; mi < 4; ++mi) {
        f32x4 z = {0.f, 0.f, 0.f, 0.f};
        z = __builtin_amdgcn_mfma_f32_16x16x32_bf16(ak[ni][0], bq[mi][0], z, 0, 0, 0);
        st[ni][mi] = __builtin_amdgcn_mfma_f32_16x16x32_bf16(ak[ni][1], bq[mi][1], z, 0, 0, 0);
      }
    float tm[4], sc[4];
    #pragma unroll
    for (int mi = 0; mi < 4; ++mi) {
      float mx = st[0][mi][0];
      #pragma unroll
      for (int ni = 0; ni < 4; ++ni)
        #pragma unroll
        for (int r = 0; r < 4; ++r) mx = fmaxf(mx, st[ni][mi][r]);
      mx = fmaxf(mx, __shfl_xor(mx, 16));
      mx = fmaxf(mx, __shfl_xor(mx, 32));
      tm[mi] = mx;
    }
    #pragma unroll
    for (int mi = 0; mi < 4; ++mi) {
      float mn = fmaxf(m_run[mi], tm[mi]);
      sc[mi] = __expf(m_run[mi] - mn);
      m_run[mi] = mn;
    }
    #pragma unroll
    for (int mi = 0; mi < 4; ++mi) {
      float rsum = 0.f;
      int q = mi * 16 + li;
      #pragma unroll
      for (int ni = 0; ni < 4; ++ni) {
        u16x4 pk;
        #pragma unroll
        for (int r = 0; r < 4; ++r) {
          float p = __expf(st[ni][mi][r] - m_run[mi]);
          rsum += p;
          pk[r] = f2bf(p);
        }
        int off = q * 128 + ((((ni * 16 + g4 * 4) * 2)) ^ ((q & 7) << 4));
        *(u16x4*)((char*)myp + off) = pk;
      }
      rsum += __shfl_xor(rsum, 16);
      rsum += __shfl_xor(rsum, 32);
      l_run[mi] = l_run[mi] * sc[mi] + rsum;
    }
    // rescale O: factor for row q_sub = g4*4+r comes from lane g4*4+r
    #pragma unroll
    for (int mi = 0; mi < 4; ++mi) {
      float f0 = __shfl(sc[mi], g4 * 4 + 0);
      float f1 = __shfl(sc[mi], g4 * 4 + 1);
      float f2s = __shfl(sc[mi], g4 * 4 + 2);
      float f3 = __shfl(sc[mi], g4 * 4 + 3);
      #pragma unroll
      for (int di = 0; di < 4; ++di) {
        o[mi][di][0] *= f0; o[mi][di][1] *= f1; o[mi][di][2] *= f2s; o[mi][di][3] *= f3;
      }
    }
    // PV: O[q][dh] += P[q][key] * V[key][dh]; A = P from LDS, B = V^T rows (contiguous keys)
    const u16* vbase = vT + (size_t)(h * DHEAD) * NTOK + kb;
    #pragma unroll
    for (int ki = 0; ki < 2; ++ki) {
      s16x8 ap[4], bv[4];
      #pragma unroll
      for (int mi = 0; mi < 4; ++mi) {
        int q = mi * 16 + li;
        int off = q * 128 + ((((ki * 32 + g4 * 8) * 2)) ^ ((q & 7) << 4));
        ap[mi] = *(const s16x8*)((char*)myp + off);
      }
      #pragma unroll
      for (int di = 0; di < 4; ++di)
        bv[di] = *(const s16x8*)(vbase + (size_t)(di * 16 + li) * NTOK + ki * 32 + g4 * 8);
      #pragma unroll
      for (int mi = 0; mi < 4; ++mi)
        #pragma unroll
        for (int di = 0; di < 4; ++di)
          o[mi][di] = __builtin_amdgcn_mfma_f32_16x16x32_bf16(ap[mi], bv[di], o[mi][di], 0, 0, 0);
    }
  }
  // merge 4 waves' online-softmax states
  if (g4 == 0) {
    #pragma unroll
    for (int mi = 0; mi < 4; ++mi) {
      ml_lds[wid][0][mi * 16 + li] = m_run[mi];
      ml_lds[wid][1][mi * 16 + li] = l_run[mi];
    }
  }
  __syncthreads();
  float fw[4];
  #pragma unroll
  for (int mi = 0; mi < 4; ++mi) {
    int q = mi * 16 + li;
    float mt = fmaxf(fmaxf(ml_lds[0][0][q], ml_lds[1][0][q]),
                     fmaxf(ml_lds[2][0][q], ml_lds[3][0][q]));
    fw[mi] = __expf(m_run[mi] - mt);
  }
  #pragma unroll
  for (int mi = 0; mi < 4; ++mi) {
    float f0 = __shfl(fw[mi], g4 * 4 + 0);
    float f1 = __shfl(fw[mi], g4 * 4 + 1);
    float f2s = __shfl(fw[mi], g4 * 4 + 2);
    float f3 = __shfl(fw[mi], g4 * 4 + 3);
    #pragma unroll
    for (int di = 0; di < 4; ++di) {
      o[mi][di][0] *= f0; o[mi][di][1] *= f1; o[mi][di][2] *= f2s; o[mi][di][3] *= f3;
    }
  }
  for (int w = 0; w < 4; ++w) {
    if (wid == w) {
      #pragma unroll
      for (int mi = 0; mi < 4; ++mi)
        #pragma unroll
        for (int di = 0; di < 4; ++di)
          #pragma unroll
          for (int r = 0; r < 4; ++r) {
            int row = mi * 16 + g4 * 4 + r, col = di * 16 + li;
            if (w == 0) o_lds[row][col] = o[mi][di][r];
            else        o_lds[row][col] += o[mi][di][r];
          }
    }
    __syncthreads();
  }
  int row = tid >> 2, cg = (tid & 3) * 16;
  float mt = fmaxf(fmaxf(ml_lds[0][0][row], ml_lds[1][0][row]),
                   fmaxf(ml_lds[2][0][row], ml_lds[3][0][row]));
  float lt = 0.f;
  #pragma unroll
  for (int w = 0; w < 4; ++w)
    lt += ml_lds[w][1][row] * __expf(ml_lds[w][0][row] - mt);
  float rcp = 1.0f / lt;
  float* dst = xt + (size_t)(q0 + row) * DMODEL + h * DHEAD + cg;
  #pragma unroll
  for (int c = 0; c < 16; ++c) dst[c] += o_lds[row][cg + c] * rcp;
}

extern "C" void kernel_launch(void* const* d_in, const int* in_sizes, int n_in,
                              void* d_out, int out_size, void* d_ws, size_t ws_size,
                              hipStream_t stream) {
  const float* x   = (const float*)d_in[0];
  const float* emb = (const float*)d_in[1];
  const float* Wq  = (const float*)d_in[2];
  const float* Wk  = (const float*)d_in[3];
  const float* Wv  = (const float*)d_in[4];
  const float* g1  = (const float*)d_in[5];
  const float* b1  = (const float*)d_in[6];
  const float* g2  = (const float*)d_in[7];
  const float* b2  = (const float*)d_in[8];
  const float* g3  = (const float*)d_in[9];
  const float* b3  = (const float*)d_in[10];
  const float* Wf1 = (const float*)d_in[11];
  const float* bf1 = (const float*)d_in[12];
  const float* Wf2 = (const float*)d_in[13];
  const float* bf2 = (const float*)d_in[14];
  float* out = (float*)d_out;

  char* ws = (char*)d_ws;
  size_t off = 0;
  auto alloc = [&](size_t bytes) { void* p = ws + off; off += (bytes + 255) & ~255ull; return p; };
  float* xt = (float*)alloc((size_t)NTOK * DMODEL * 4);
  u16* qkin = (u16*)alloc((size_t)NTOK * DCAT * 2);
  u16* hb   = (u16*)alloc((size_t)NTOK * DMODEL * 2);
  u16* r1   = (u16*)alloc((size_t)NTOK * DMODEL * 2);
  u16* qhd  = (u16*)alloc((size_t)NTOK * DMODEL * 2);
  u16* khd  = (u16*)alloc((size_t)NTOK * DMODEL * 2);
  u16* vTd  = (u16*)alloc((size_t)NTOK * DMODEL * 2);
  u16* Tq   = (u16*)alloc((size_t)DCAT * DMODEL * 2);
  u16* Tk   = (u16*)alloc((size_t)DCAT * DMODEL * 2);
  u16* Tv   = (u16*)alloc((size_t)DMODEL * DMODEL * 2);
  u16* Tf1  = (u16*)alloc((size_t)DMODEL * DMODEL * 2);
  u16* Tf2  = (u16*)alloc((size_t)DMODEL * DMODEL * 2);

  wtrans_kernel<<<dim3(9, 8, 5), 256, 0, stream>>>(Wq, Wk, Wv, Wf1, Wf2, Tq, Tk, Tv, Tf1, Tf2);
  lnx_kernel<<<1024, 256, 0, stream>>>(x, g1, b1, xt, qkin);
  lne_kernel<<<1024, 256, 0, stream>>>(emb, g2, b2, qkin);
  gemm_kernel<0><<<256, 256, 0, stream>>>(qkin, DCAT, Tq, DCAT, qhd, nullptr, nullptr, nullptr);
  gemm_kernel<1><<<256, 256, 0, stream>>>(qkin, DCAT, Tk, DCAT, khd, nullptr, nullptr, nullptr);
  gemm_kernel<2><<<256, 256, 0, stream>>>(qkin, DCAT, Tv, DMODEL, vTd, nullptr, nullptr, nullptr);
  attn_kernel<<<512, 256, 0, stream>>>(qhd, khd, vTd, xt);
  ln3_kernel<<<1024, 256, 0, stream>>>(xt, g3, b3, hb);
  gemm_kernel<3><<<256, 256, 0, stream>>>(hb, DMODEL, Tf1, DMODEL, r1, nullptr, bf1, nullptr);
  gemm_kernel<4><<<256, 256, 0, stream>>>(r1, DMODEL, Tf2, DMODEL, nullptr, out, bf2, xt);
}